// Round 15
// baseline (579.308 us; speedup 1.0000x reference)
//
#include <hip/hip_runtime.h>

// ---------------------------------------------------------------------------
// TiedMultiheadAttention  (B=1, N=64, L=512, D=768, H=12, DK=64)
//
// R17: R14 config restored exactly (best, 565.3us: s5 on gemm256 OUT_BIAS).
//      ONE isolated change: s4 (att@V^T) moved to gemm256o — a STANDALONE
//      clone of the gemm256 K-loop with the OUTWS map hard-wired, so the
//      gemm256 template's instantiation set stays byte-identical to R14
//      (rule #19: R15's regression was s1b codegen perturbation from the
//      added OUTWS instantiation, not the engine move). gemm_bt retired.
// ---------------------------------------------------------------------------

typedef __bf16 bf16x8 __attribute__((ext_vector_type(8)));
typedef float f32x4 __attribute__((ext_vector_type(4)));

__device__ __forceinline__ unsigned short f2bf(float f) {
  unsigned u = __float_as_uint(f);
  u += 0x7fffu + ((u >> 16) & 1u);  // RNE
  return (unsigned short)(u >> 16);
}

__device__ __forceinline__ void gll16(const void* g, void* l) {
  __builtin_amdgcn_global_load_lds(
      (const __attribute__((address_space(1))) unsigned int*)g,
      (__attribute__((address_space(3))) unsigned int*)l, 16, 0, 0);
}

#define BAR __builtin_amdgcn_s_barrier()

enum { MODE_QCAT = 0, MODE_VT = 1, MODE_ATT = 2, MODE_OUTWS = 3, MODE_OUT_BIAS = 4 };

// ========================= gemm256: 256x256x64, 8 waves =====================
// C = A @ B^T, A:[M,K] bf16, B:[N,K] bf16. Per-wave 128x64 output, acc[8][4].
// LDS: 2 buf x (A,B) x 32KB = 128 KiB. Stage unit = 8KB quarter (64 rows x 64
// cols) = 1 gll/wave. Slot-XOR involution on A/B reads (source pre-swizzled).
// Per tile T (4 phases, kc=p>>1, mhalf=p&1):
//   p0: stage B0,B1(T+1)   p1: stage B2,B3(T+1)
//   p2: stage A1,A3(T+1)   p3: stage A0,A2(T+2)
// Boundary: vmcnt(2) (the two T+2 quarters stay in flight), barrier.
// Block maps:
//   QCAT/VT/OUT_BIAS: generic XCD swizzle (ntn), batch = blockIdx.z.
//   ATT: grid (4,1,48): x -> tm=x>>1, tn=x&1; z -> head=z%12, ks=z/12;
//        K = 1024 slice, A/B advanced by ks*K; C = fp32 partial [ks*12+h].
template <int MODE>
__global__ __launch_bounds__(512, 2) void gemm256(
    const void* __restrict__ Av, const void* __restrict__ Bv,
    const float* __restrict__ b0, const float* __restrict__ b1,
    void* __restrict__ Cv, int K, int lda, int ldb,
    long long a_bs, long long b_bs, float alpha0, float alpha1,
    long long c_bs, int ntn) {
  __shared__ unsigned short L[2][2][16384];

  const int tid = threadIdx.x;
  const int wave = tid >> 6;
  const int lane = tid & 63;
  const int wm = wave >> 2;   // 0..1
  const int wn = wave & 3;    // 0..3
  const int l15 = lane & 15;
  const int kq8 = lane >> 4;  // 0..3
  const int sw = l15 & 7;

  int tm, tn, batch, ks = 0;
  if constexpr (MODE == MODE_ATT) {
    tm = blockIdx.x >> 1;
    tn = blockIdx.x & 1;
    batch = blockIdx.z % 12;   // head
    ks = blockIdx.z / 12;      // 0..3 split-K slice
  } else {
    const int bid = blockIdx.x;
    const int xcd = bid & 7;
    const int kk_ = bid >> 3;
    tn = kk_ % ntn;
    tm = (kk_ / ntn) * 8 + xcd;
    batch = blockIdx.z;
  }

  const long long m0 = (long long)tm * 256;
  const long long n0 = (long long)tn * 256;

  const unsigned short* Ab = (const unsigned short*)Av + (long long)batch * a_bs +
                             (long long)ks * K;
  const unsigned short* Bb = (const unsigned short*)Bv + (long long)batch * b_bs +
                             (long long)ks * K;

  const long long rowAw = m0 + wave * 8 + (lane >> 3);
  const long long rowBw = n0 + wave * 8 + (lane >> 3);
  const int csw = ((lane & 7) ^ (lane >> 3)) << 3;  // pre-swizzled col (elems)

  f32x4 acc[8][4] = {};

  auto stA = [&](int buf, int q, int k0) {
    gll16(Ab + (rowAw + (q << 6)) * (long long)lda + k0 + csw,
          &L[buf][0][(q << 12) + (wave << 9)]);
  };
  auto stB = [&](int buf, int q, int k0) {
    gll16(Bb + (rowBw + (q << 6)) * (long long)ldb + k0 + csw,
          &L[buf][1][(q << 12) + (wave << 9)]);
  };

  // bias preload (no VMEM inside the K-loop except staging glls)
  float bpre[4] = {};
  float aa = 1.0f;
  if constexpr (MODE == MODE_QCAT || MODE == MODE_VT || MODE == MODE_OUT_BIAS) {
    const float* bb = batch ? b1 : b0;
    aa = batch ? alpha1 : alpha0;
#pragma unroll
    for (int u = 0; u < 4; ++u) bpre[u] = bb[n0 + wn * 64 + u * 16 + l15];
  }

  // Prologue: tile 0 fully, then A0,A2 of tile 1 (the 2 allowed in flight).
  const int NT = K >> 6;
#pragma unroll
  for (int q = 0; q < 4; ++q) stB(0, q, 0);
#pragma unroll
  for (int q = 0; q < 4; ++q) stA(0, q, 0);
  if (NT > 1) {
    stA(1, 0, 64);
    stA(1, 2, 64);
    asm volatile("s_waitcnt vmcnt(2)" ::: "memory");
  } else {
    asm volatile("s_waitcnt vmcnt(0)" ::: "memory");
  }
  BAR;

  for (int T = 0; T < NT; ++T) {
    const int cur = T & 1, nxt = cur ^ 1;
    const int k1 = (T + 1) << 6, k2 = (T + 2) << 6;
#pragma unroll
    for (int p = 0; p < 4; ++p) {
      const int kc = p >> 1, mh = p & 1;
      bf16x8 af[4], bfr[4];
#pragma unroll
      for (int mf = 0; mf < 4; ++mf) {
        const int row = wm * 128 + mh * 64 + mf * 16 + l15;
        af[mf] = *(const bf16x8*)&L[cur][0][row * 64 + (((kc << 2) + kq8) ^ sw) * 8];
      }
#pragma unroll
      for (int u = 0; u < 4; ++u) {
        const int row = wn * 64 + u * 16 + l15;
        bfr[u] = *(const bf16x8*)&L[cur][1][row * 64 + (((kc << 2) + kq8) ^ sw) * 8];
      }
      if (p == 0 && T + 1 < NT) { stB(nxt, 0, k1); stB(nxt, 1, k1); }
      if (p == 1 && T + 1 < NT) { stB(nxt, 2, k1); stB(nxt, 3, k1); }
      if (p == 2 && T + 1 < NT) { stA(nxt, 1, k1); stA(nxt, 3, k1); }
      if (p == 3 && T + 2 < NT) { stA(cur, 0, k2); stA(cur, 2, k2); }
      __builtin_amdgcn_s_setprio(1);
#pragma unroll
      for (int mf = 0; mf < 4; ++mf)
#pragma unroll
        for (int u = 0; u < 4; ++u)
          acc[mh * 4 + mf][u] = __builtin_amdgcn_mfma_f32_16x16x32_bf16(
              af[mf], bfr[u], acc[mh * 4 + mf][u], 0, 0, 0);
      __builtin_amdgcn_s_setprio(0);
      if (p == 3) {
        if (T + 1 < NT) {
          if (T + 2 < NT) asm volatile("s_waitcnt vmcnt(2)" ::: "memory");
          else            asm volatile("s_waitcnt vmcnt(0)" ::: "memory");
          BAR;
        }
      } else {
        BAR;
      }
    }
  }

  // Epilogue
#pragma unroll
  for (int mf = 0; mf < 8; ++mf) {
#pragma unroll
    for (int u = 0; u < 4; ++u) {
      const long long col = n0 + wn * 64 + u * 16 + l15;
#pragma unroll
      for (int r = 0; r < 4; ++r) {
        const long long row = m0 + wm * 128 + mf * 16 + (lane >> 4) * 4 + r;
        float v = acc[mf][u][r];
        if constexpr (MODE == MODE_QCAT) {
          const float vv = (v + bpre[u]) * aa;
          const long long h = col >> 6, kq = col & 63, n = row >> 9, i = row & 511;
          ((unsigned short*)Cv + batch * c_bs)[((h * 512 + i) << 12) + (n << 6) + kq] =
              f2bf(vv);
        } else if constexpr (MODE == MODE_VT) {
          const float vv = v + bpre[u];
          const long long h = col >> 6, kq = col & 63, n = row >> 9, j = row & 511;
          ((unsigned short*)Cv)[(((h << 12) + (n << 6) + kq) << 9) + j] = f2bf(vv);
        } else if constexpr (MODE == MODE_ATT) {
          // fp32 partial [ks*12+head][i][j], plain coalesced stores
          ((float*)Cv)[((long long)(ks * 12 + batch) << 18) + (row << 9) + col] = v;
        } else {  // MODE_OUT_BIAS
          ((float*)Cv)[row * 768 + col] = v + bpre[u];
        }
      }
    }
  }
}

// ============ gemm256o: standalone clone for s4 (att @ V^T, OUTWS) ==========
// Identical K-loop to gemm256; block map and epilogue hard-wired:
// grid (32,1,12): tm=x>>4, tn=x&15, batch=head=z. M=512, N=4096, K=512.
// Separate function so gemm256's instantiation set (and thus s1b's codegen)
// stays byte-identical to R14 (rule #19).
__global__ __launch_bounds__(512, 2) void gemm256o(
    const void* __restrict__ Av, const void* __restrict__ Bv,
    void* __restrict__ Cv, int K, int lda, int ldb,
    long long a_bs, long long b_bs) {
  __shared__ unsigned short L[2][2][16384];

  const int tid = threadIdx.x;
  const int wave = tid >> 6;
  const int lane = tid & 63;
  const int wm = wave >> 2;   // 0..1
  const int wn = wave & 3;    // 0..3
  const int l15 = lane & 15;
  const int kq8 = lane >> 4;  // 0..3
  const int sw = l15 & 7;

  const int tm = blockIdx.x >> 4;   // 0..1
  const int tn = blockIdx.x & 15;   // 0..15
  const int batch = blockIdx.z;     // head

  const long long m0 = (long long)tm * 256;
  const long long n0 = (long long)tn * 256;

  const unsigned short* Ab = (const unsigned short*)Av + (long long)batch * a_bs;
  const unsigned short* Bb = (const unsigned short*)Bv + (long long)batch * b_bs;

  const long long rowAw = m0 + wave * 8 + (lane >> 3);
  const long long rowBw = n0 + wave * 8 + (lane >> 3);
  const int csw = ((lane & 7) ^ (lane >> 3)) << 3;

  f32x4 acc[8][4] = {};

  auto stA = [&](int buf, int q, int k0) {
    gll16(Ab + (rowAw + (q << 6)) * (long long)lda + k0 + csw,
          &L[buf][0][(q << 12) + (wave << 9)]);
  };
  auto stB = [&](int buf, int q, int k0) {
    gll16(Bb + (rowBw + (q << 6)) * (long long)ldb + k0 + csw,
          &L[buf][1][(q << 12) + (wave << 9)]);
  };

  const int NT = K >> 6;
#pragma unroll
  for (int q = 0; q < 4; ++q) stB(0, q, 0);
#pragma unroll
  for (int q = 0; q < 4; ++q) stA(0, q, 0);
  if (NT > 1) {
    stA(1, 0, 64);
    stA(1, 2, 64);
    asm volatile("s_waitcnt vmcnt(2)" ::: "memory");
  } else {
    asm volatile("s_waitcnt vmcnt(0)" ::: "memory");
  }
  BAR;

  for (int T = 0; T < NT; ++T) {
    const int cur = T & 1, nxt = cur ^ 1;
    const int k1 = (T + 1) << 6, k2 = (T + 2) << 6;
#pragma unroll
    for (int p = 0; p < 4; ++p) {
      const int kc = p >> 1, mh = p & 1;
      bf16x8 af[4], bfr[4];
#pragma unroll
      for (int mf = 0; mf < 4; ++mf) {
        const int row = wm * 128 + mh * 64 + mf * 16 + l15;
        af[mf] = *(const bf16x8*)&L[cur][0][row * 64 + (((kc << 2) + kq8) ^ sw) * 8];
      }
#pragma unroll
      for (int u = 0; u < 4; ++u) {
        const int row = wn * 64 + u * 16 + l15;
        bfr[u] = *(const bf16x8*)&L[cur][1][row * 64 + (((kc << 2) + kq8) ^ sw) * 8];
      }
      if (p == 0 && T + 1 < NT) { stB(nxt, 0, k1); stB(nxt, 1, k1); }
      if (p == 1 && T + 1 < NT) { stB(nxt, 2, k1); stB(nxt, 3, k1); }
      if (p == 2 && T + 1 < NT) { stA(nxt, 1, k1); stA(nxt, 3, k1); }
      if (p == 3 && T + 2 < NT) { stA(cur, 0, k2); stA(cur, 2, k2); }
      __builtin_amdgcn_s_setprio(1);
#pragma unroll
      for (int mf = 0; mf < 4; ++mf)
#pragma unroll
        for (int u = 0; u < 4; ++u)
          acc[mh * 4 + mf][u] = __builtin_amdgcn_mfma_f32_16x16x32_bf16(
              af[mf], bfr[u], acc[mh * 4 + mf][u], 0, 0, 0);
      __builtin_amdgcn_s_setprio(0);
      if (p == 3) {
        if (T + 1 < NT) {
          if (T + 2 < NT) asm volatile("s_waitcnt vmcnt(2)" ::: "memory");
          else            asm volatile("s_waitcnt vmcnt(0)" ::: "memory");
          BAR;
        }
      } else {
        BAR;
      }
    }
  }

  // Epilogue: out_ws[(n*512+i)*768 + head*64 + kk]
#pragma unroll
  for (int mf = 0; mf < 8; ++mf) {
#pragma unroll
    for (int u = 0; u < 4; ++u) {
      const long long col = n0 + wn * 64 + u * 16 + l15;
#pragma unroll
      for (int r = 0; r < 4; ++r) {
        const long long row = m0 + wm * 128 + mf * 16 + (lane >> 4) * 4 + r;
        const long long n = col >> 6, kk = col & 63;
        ((unsigned short*)Cv)[(n * 512 + row) * 768 + (long long)batch * 64 + kk] =
            f2bf(acc[mf][u][r]);
      }
    }
  }
}

// softmax over last dim with 4-way split-K partial sum:
// att fp32 partials [4][12][512][512] -> bf16 [12][512][512]
__global__ __launch_bounds__(256) void softmax_rows(const float* __restrict__ att,
                                                    unsigned short* __restrict__ outb) {
  const long long rowbase = (long long)blockIdx.x << 9;
  const int tid = threadIdx.x;
  float a = 0.0f, b = 0.0f;
#pragma unroll
  for (int s = 0; s < 4; ++s) {
    a += att[(long long)s * 3145728 + rowbase + tid];
    b += att[(long long)s * 3145728 + rowbase + tid + 256];
  }

  float m = fmaxf(a, b);
#pragma unroll
  for (int off = 32; off; off >>= 1) m = fmaxf(m, __shfl_down(m, off));
  __shared__ float redm[4];
  if ((tid & 63) == 0) redm[tid >> 6] = m;
  __syncthreads();
  m = fmaxf(fmaxf(redm[0], redm[1]), fmaxf(redm[2], redm[3]));

  const float e0 = __expf(a - m), e1 = __expf(b - m);
  float s = e0 + e1;
#pragma unroll
  for (int off = 32; off; off >>= 1) s += __shfl_down(s, off);
  __shared__ float reds[4];
  if ((tid & 63) == 0) reds[tid >> 6] = s;
  __syncthreads();
  s = reds[0] + reds[1] + reds[2] + reds[3];

  const float inv = 1.0f / s;
  outb[rowbase + tid] = f2bf(e0 * inv);
  outb[rowbase + tid + 256] = f2bf(e1 * inv);
}

// Fused fp32 -> bf16 for ALL seven tensors, MLP-optimized: 64 elems/thread,
// 16 independent lane-contiguous nontemporal float4 loads, 16 uint2 stores.
// Grid 4752: Q/K/V = 1536 blocks each; 4 weights = 36 blocks each.
__global__ __launch_bounds__(256) void cvt_all(
    const float* __restrict__ q, const float* __restrict__ k,
    const float* __restrict__ v, const float* __restrict__ wq,
    const float* __restrict__ wk, const float* __restrict__ wv,
    const float* __restrict__ wo, unsigned short* __restrict__ dq,
    unsigned short* __restrict__ dk, unsigned short* __restrict__ dv,
    unsigned short* __restrict__ dwq, unsigned short* __restrict__ dwk,
    unsigned short* __restrict__ dwv, unsigned short* __restrict__ dwo) {
  const int b = blockIdx.x;
  const float* s;
  unsigned short* d;
  long long blk;
  if (b < 1536) { s = q; d = dq; blk = b; }
  else if (b < 3072) { s = k; d = dk; blk = b - 1536; }
  else if (b < 4608) { s = v; d = dv; blk = b - 3072; }
  else {
    const int w = b - 4608;
    const int t = w / 36;
    blk = w % 36;
    s = t == 0 ? wq : (t == 1 ? wk : (t == 2 ? wv : wo));
    d = t == 0 ? dwq : (t == 1 ? dwk : (t == 2 ? dwv : dwo));
  }
  const long long base = blk * 16384;
  const int tid = threadIdx.x;

  f32x4 r[16];
#pragma unroll
  for (int c = 0; c < 16; ++c)
    r[c] = __builtin_nontemporal_load(
        (const f32x4*)(s + base + (long long)(c * 256 + tid) * 4));
#pragma unroll
  for (int c = 0; c < 16; ++c) {
    uint2 p;
    p.x = (unsigned)f2bf(r[c][0]) | ((unsigned)f2bf(r[c][1]) << 16);
    p.y = (unsigned)f2bf(r[c][2]) | ((unsigned)f2bf(r[c][3]) << 16);
    *(uint2*)(d + base + (long long)(c * 256 + tid) * 4) = p;
  }
}

extern "C" void kernel_launch(void* const* d_in, const int* in_sizes, int n_in,
                              void* d_out, int out_size, void* d_ws, size_t ws_size,
                              hipStream_t stream) {
  const float* query = (const float*)d_in[0];
  const float* key   = (const float*)d_in[1];
  const float* value = (const float*)d_in[2];
  const float* Wq = (const float*)d_in[3];
  const float* bq = (const float*)d_in[4];
  const float* Wk = (const float*)d_in[5];
  const float* bk = (const float*)d_in[6];
  const float* Wv = (const float*)d_in[7];
  const float* bv = (const float*)d_in[8];
  const float* Wo = (const float*)d_in[9];
  const float* bo = (const float*)d_in[10];
  float* out = (float*)d_out;

  char* ws = (char*)d_ws;
  unsigned short* q_ws  = (unsigned short*)(ws);               // 50,331,648 B
  unsigned short* k_ws  = (unsigned short*)(ws + 50331648);    // 50,331,648 B
  unsigned short* vt_ws = (unsigned short*)(ws + 100663296);   // 50,331,648 B
  // bf16 weights, contiguous (b_bs = 589824 shorts strides wq->wk->wv)
  unsigned short* wq_b  = (unsigned short*)(ws + 150994944);
  unsigned short* wk_b  = (unsigned short*)(ws + 150994944 + 1179648);
  unsigned short* wv_b  = (unsigned short*)(ws + 150994944 + 2359296);
  unsigned short* wo_b  = (unsigned short*)(ws + 150994944 + 3538944);
  unsigned short* att_b = k_ws;   // k_ws dead after s2
  unsigned short* out_ws = q_ws;  // q_ws dead after s2
  // d_out scratch: xb0/xb1 bf16 Q/K inputs (dead after s1b);
  // att partials overlay xb1's region (xb1 dead after s1b).
  unsigned short* xb0 = (unsigned short*)d_out;                 // 50,331,648 B
  unsigned short* xb1 = (unsigned short*)d_out + 25165824;      // 50,331,648 B
  // V-bf16 input parks in k_ws: consumed by s1c (V-proj) BEFORE s1b
  // overwrites k_ws with the K projection (stream-serialized).
  unsigned short* xbv = k_ws;
  float* att_part = (float*)((char*)d_out + 50331648);          // 4 x 12,582,912 B

  const dim3 blk(256);
  const dim3 blk5(512);

  // s0: ALL fp32 -> bf16 conversions in one MLP-deep launch.
  cvt_all<<<4752, blk, 0, stream>>>(query, key, value, Wq, Wk, Wv, Wo,
                                    xb0, xb1, xbv, wq_b, wk_b, wv_b, wo_b);

  // s1c: V projection FIRST (reads xbv=k_ws, writes vt_ws)
  gemm256<MODE_VT><<<dim3(384, 1, 1), blk5, 0, stream>>>(
      xbv, wv_b, bv, nullptr, vt_ws, 768, 768, 768, 0, 0, 1.0f, 1.0f, 0, 3);

  // s1b: Q and K projections batched (z=2); batch1 output overwrites k_ws
  gemm256<MODE_QCAT><<<dim3(384, 1, 2), blk5, 0, stream>>>(
      xb0, wq_b, bq, bk, q_ws, 768, 768, 768, 25165824LL, 589824LL,
      0.015625f, 1.0f, 25165824LL, 3);

  // s2: tied scores on gemm256, per-head [512 x 4096] @ [512 x 4096]^T,
  //     split-K x4 (K-slice 1024, NT=16) -> 4 plain partial buffers
  //     in d_out's second half.
  gemm256<MODE_ATT><<<dim3(4, 1, 48), blk5, 0, stream>>>(
      q_ws, k_ws, nullptr, nullptr, att_part, 1024, 4096, 4096,
      2097152LL, 2097152LL, 1.0f, 1.0f, 0, 0);

  // s3: softmax (sums the 4 partials)
  softmax_rows<<<6144, blk, 0, stream>>>(att_part, att_b);

  // s4: per-head att @ Vt^T on the standalone gemm256o clone:
  //     M=512, N=4096, K=512 (NT=8), grid (32,1,12)
  gemm256o<<<dim3(32, 1, 12), blk5, 0, stream>>>(
      att_b, vt_ws, out_ws, 512, 512, 512, 262144LL, 2097152LL);

  // s5: output projection -> fp32 d_out on gemm256 (R14 config)
  gemm256<MODE_OUT_BIAS><<<dim3(384, 1, 1), blk5, 0, stream>>>(
      out_ws, wo_b, bo, nullptr, out, 768, 768, 768, 0, 0, 1.0f, 1.0f, 0, 3);
}

// Round 16
// 572.991 us; speedup vs baseline: 1.0110x; 1.0110x over previous
//
#include <hip/hip_runtime.h>

// ---------------------------------------------------------------------------
// TiedMultiheadAttention  (B=1, N=64, L=512, D=768, H=12, DK=64)
//
// R18 == R14 (best measured, 565.3us), locked in after isolated A/Bs
// R15-R17 each regressed it. Final engine map:
//   cvt_all (MLP-deep fused fp32->bf16) -> s1c VT / s1b QCATx2 on gemm256
//   -> s2 ATT on gemm256 (split-K x4, NT=16, plain partials in d_out)
//   -> softmax (sums 4 partials) -> s4 OUTWS on gemm_bt (locality map)
//   -> s5 OUT_BIAS on gemm256.
// ---------------------------------------------------------------------------

typedef __bf16 bf16x8 __attribute__((ext_vector_type(8)));
typedef float f32x4 __attribute__((ext_vector_type(4)));

__device__ __forceinline__ unsigned short f2bf(float f) {
  unsigned u = __float_as_uint(f);
  u += 0x7fffu + ((u >> 16) & 1u);  // RNE
  return (unsigned short)(u >> 16);
}

__device__ __forceinline__ void gll16(const void* g, void* l) {
  __builtin_amdgcn_global_load_lds(
      (const __attribute__((address_space(1))) unsigned int*)g,
      (__attribute__((address_space(3))) unsigned int*)l, 16, 0, 0);
}

#define BAR __builtin_amdgcn_s_barrier()

enum { MODE_QCAT = 0, MODE_VT = 1, MODE_ATT = 2, MODE_OUTWS = 3, MODE_OUT_BIAS = 4 };

// ========================= gemm256: 256x256x64, 8 waves =====================
// C = A @ B^T, A:[M,K] bf16, B:[N,K] bf16. Per-wave 128x64 output, acc[8][4].
// LDS: 2 buf x (A,B) x 32KB = 128 KiB. Stage unit = 8KB quarter (64 rows x 64
// cols) = 1 gll/wave. Slot-XOR involution on A/B reads (source pre-swizzled).
// Per tile T (4 phases, kc=p>>1, mhalf=p&1):
//   p0: stage B0,B1(T+1)   p1: stage B2,B3(T+1)
//   p2: stage A1,A3(T+1)   p3: stage A0,A2(T+2)
// Boundary: vmcnt(2) (the two T+2 quarters stay in flight), barrier.
// Block maps:
//   QCAT/VT/OUT_BIAS: generic XCD swizzle (ntn), batch = blockIdx.z.
//   ATT: grid (4,1,48): x -> tm=x>>1, tn=x&1; z -> head=z%12, ks=z/12;
//        K = 1024 slice, A/B advanced by ks*K; C = fp32 partial [ks*12+h].
template <int MODE>
__global__ __launch_bounds__(512, 2) void gemm256(
    const void* __restrict__ Av, const void* __restrict__ Bv,
    const float* __restrict__ b0, const float* __restrict__ b1,
    void* __restrict__ Cv, int K, int lda, int ldb,
    long long a_bs, long long b_bs, float alpha0, float alpha1,
    long long c_bs, int ntn) {
  __shared__ unsigned short L[2][2][16384];

  const int tid = threadIdx.x;
  const int wave = tid >> 6;
  const int lane = tid & 63;
  const int wm = wave >> 2;   // 0..1
  const int wn = wave & 3;    // 0..3
  const int l15 = lane & 15;
  const int kq8 = lane >> 4;  // 0..3
  const int sw = l15 & 7;

  int tm, tn, batch, ks = 0;
  if constexpr (MODE == MODE_ATT) {
    tm = blockIdx.x >> 1;
    tn = blockIdx.x & 1;
    batch = blockIdx.z % 12;   // head
    ks = blockIdx.z / 12;      // 0..3 split-K slice
  } else {
    const int bid = blockIdx.x;
    const int xcd = bid & 7;
    const int kk_ = bid >> 3;
    tn = kk_ % ntn;
    tm = (kk_ / ntn) * 8 + xcd;
    batch = blockIdx.z;
  }

  const long long m0 = (long long)tm * 256;
  const long long n0 = (long long)tn * 256;

  const unsigned short* Ab = (const unsigned short*)Av + (long long)batch * a_bs +
                             (long long)ks * K;
  const unsigned short* Bb = (const unsigned short*)Bv + (long long)batch * b_bs +
                             (long long)ks * K;

  const long long rowAw = m0 + wave * 8 + (lane >> 3);
  const long long rowBw = n0 + wave * 8 + (lane >> 3);
  const int csw = ((lane & 7) ^ (lane >> 3)) << 3;  // pre-swizzled col (elems)

  f32x4 acc[8][4] = {};

  auto stA = [&](int buf, int q, int k0) {
    gll16(Ab + (rowAw + (q << 6)) * (long long)lda + k0 + csw,
          &L[buf][0][(q << 12) + (wave << 9)]);
  };
  auto stB = [&](int buf, int q, int k0) {
    gll16(Bb + (rowBw + (q << 6)) * (long long)ldb + k0 + csw,
          &L[buf][1][(q << 12) + (wave << 9)]);
  };

  // bias preload (no VMEM inside the K-loop except staging glls)
  float bpre[4] = {};
  float aa = 1.0f;
  if constexpr (MODE == MODE_QCAT || MODE == MODE_VT || MODE == MODE_OUT_BIAS) {
    const float* bb = batch ? b1 : b0;
    aa = batch ? alpha1 : alpha0;
#pragma unroll
    for (int u = 0; u < 4; ++u) bpre[u] = bb[n0 + wn * 64 + u * 16 + l15];
  }

  // Prologue: tile 0 fully, then A0,A2 of tile 1 (the 2 allowed in flight).
  const int NT = K >> 6;
#pragma unroll
  for (int q = 0; q < 4; ++q) stB(0, q, 0);
#pragma unroll
  for (int q = 0; q < 4; ++q) stA(0, q, 0);
  if (NT > 1) {
    stA(1, 0, 64);
    stA(1, 2, 64);
    asm volatile("s_waitcnt vmcnt(2)" ::: "memory");
  } else {
    asm volatile("s_waitcnt vmcnt(0)" ::: "memory");
  }
  BAR;

  for (int T = 0; T < NT; ++T) {
    const int cur = T & 1, nxt = cur ^ 1;
    const int k1 = (T + 1) << 6, k2 = (T + 2) << 6;
#pragma unroll
    for (int p = 0; p < 4; ++p) {
      const int kc = p >> 1, mh = p & 1;
      bf16x8 af[4], bfr[4];
#pragma unroll
      for (int mf = 0; mf < 4; ++mf) {
        const int row = wm * 128 + mh * 64 + mf * 16 + l15;
        af[mf] = *(const bf16x8*)&L[cur][0][row * 64 + (((kc << 2) + kq8) ^ sw) * 8];
      }
#pragma unroll
      for (int u = 0; u < 4; ++u) {
        const int row = wn * 64 + u * 16 + l15;
        bfr[u] = *(const bf16x8*)&L[cur][1][row * 64 + (((kc << 2) + kq8) ^ sw) * 8];
      }
      if (p == 0 && T + 1 < NT) { stB(nxt, 0, k1); stB(nxt, 1, k1); }
      if (p == 1 && T + 1 < NT) { stB(nxt, 2, k1); stB(nxt, 3, k1); }
      if (p == 2 && T + 1 < NT) { stA(nxt, 1, k1); stA(nxt, 3, k1); }
      if (p == 3 && T + 2 < NT) { stA(cur, 0, k2); stA(cur, 2, k2); }
      __builtin_amdgcn_s_setprio(1);
#pragma unroll
      for (int mf = 0; mf < 4; ++mf)
#pragma unroll
        for (int u = 0; u < 4; ++u)
          acc[mh * 4 + mf][u] = __builtin_amdgcn_mfma_f32_16x16x32_bf16(
              af[mf], bfr[u], acc[mh * 4 + mf][u], 0, 0, 0);
      __builtin_amdgcn_s_setprio(0);
      if (p == 3) {
        if (T + 1 < NT) {
          if (T + 2 < NT) asm volatile("s_waitcnt vmcnt(2)" ::: "memory");
          else            asm volatile("s_waitcnt vmcnt(0)" ::: "memory");
          BAR;
        }
      } else {
        BAR;
      }
    }
  }

  // Epilogue
#pragma unroll
  for (int mf = 0; mf < 8; ++mf) {
#pragma unroll
    for (int u = 0; u < 4; ++u) {
      const long long col = n0 + wn * 64 + u * 16 + l15;
#pragma unroll
      for (int r = 0; r < 4; ++r) {
        const long long row = m0 + wm * 128 + mf * 16 + (lane >> 4) * 4 + r;
        float v = acc[mf][u][r];
        if constexpr (MODE == MODE_QCAT) {
          const float vv = (v + bpre[u]) * aa;
          const long long h = col >> 6, kq = col & 63, n = row >> 9, i = row & 511;
          ((unsigned short*)Cv + batch * c_bs)[((h * 512 + i) << 12) + (n << 6) + kq] =
              f2bf(vv);
        } else if constexpr (MODE == MODE_VT) {
          const float vv = v + bpre[u];
          const long long h = col >> 6, kq = col & 63, n = row >> 9, j = row & 511;
          ((unsigned short*)Cv)[(((h << 12) + (n << 6) + kq) << 9) + j] = f2bf(vv);
        } else if constexpr (MODE == MODE_ATT) {
          // fp32 partial [ks*12+head][i][j], plain coalesced stores
          ((float*)Cv)[((long long)(ks * 12 + batch) << 18) + (row << 9) + col] = v;
        } else {  // MODE_OUT_BIAS
          ((float*)Cv)[row * 768 + col] = v + bpre[u];
        }
      }
    }
  }
}

// ================== R5/R10 128x128 kernel (s4) ==============================
constexpr int BM = 128, BN = 128, BK = 32;

template <int MODE, bool SWZ, int KS>
__global__ __launch_bounds__(256, 2) void gemm_bt(
    const void* __restrict__ Av, const void* __restrict__ Bv,
    const float* __restrict__ bias, void* __restrict__ Cv,
    int K, int lda, int ldb, long long a_bs, long long b_bs,
    float alpha, int ntn, long long c_bs) {
  constexpr int LP = 32;

  __shared__ unsigned short As0[BM * LP];
  __shared__ unsigned short Bs0[BN * LP];
  __shared__ unsigned short As1[BM * LP];
  __shared__ unsigned short Bs1[BN * LP];

  const int tid = threadIdx.x;
  const int wave = tid >> 6;
  const int lane = tid & 63;
  const int wm = wave >> 1, wn = wave & 1;

  int tm, tn, batch = 0, ks = 0;
  if constexpr (SWZ && MODE == MODE_ATT) {
    const int bid = blockIdx.x;
    const int xcd = bid & 7, j = bid >> 3;
    const int z = (j >> 4) * 8 + xcd;   // 0..47, z%8 == xcd
    const int tile = j & 15;
    tn = tile & 3;
    tm = tile >> 2;
    ks = z % KS;
    batch = z / KS;
  } else if constexpr (SWZ && MODE == MODE_OUTWS) {
    const int bid = blockIdx.x;
    const int xcd = bid & 7, j = bid >> 3;
    const int g = (j >> 6) * 8 + xcd;   // 0..23, g%8 == xcd
    const int idx = j & 63;
    batch = g >> 1;                     // head
    tm = idx >> 4;
    tn = (g & 1) * 16 + (idx & 15);
  } else {
    tn = blockIdx.x;
    tm = blockIdx.y;
    batch = blockIdx.z;
    if constexpr (KS > 1) { ks = batch % KS; batch /= KS; }
  }

  const long long m0 = (long long)tm * BM;
  const long long n0 = (long long)tn * BN;

  const unsigned short* Ab = (const unsigned short*)Av + (long long)batch * a_bs + (long long)ks * K;
  const unsigned short* Bb = (const unsigned short*)Bv + (long long)batch * b_bs + (long long)ks * K;

  f32x4 acc[4][4] = {};

  const int l15 = lane & 15;
  const int kq = (lane >> 4) * 8;
  const int r_in = lane >> 2;
  const int c8 = (lane & 3) * 8;

  auto stage = [&](unsigned short* Asb, unsigned short* Bsb, int k0) {
#pragma unroll
    for (int t = 0; t < 2; ++t) {
      const int rb = t * 64 + wave * 16;
      gll16(Ab + (m0 + rb + r_in) * (long long)lda + k0 + c8, &Asb[rb * LP]);
      gll16(Bb + (n0 + rb + r_in) * (long long)ldb + k0 + c8, &Bsb[rb * LP]);
    }
  };
  auto compute = [&](const unsigned short* Asb, const unsigned short* Bsb) {
    bf16x8 af[4], bfr[4];
#pragma unroll
    for (int t = 0; t < 4; ++t)
      af[t] = *(const bf16x8*)&Asb[(wm * 64 + t * 16 + l15) * LP + kq];
#pragma unroll
    for (int u = 0; u < 4; ++u)
      bfr[u] = *(const bf16x8*)&Bsb[(wn * 64 + u * 16 + l15) * LP + kq];
#pragma unroll
    for (int t = 0; t < 4; ++t)
#pragma unroll
      for (int u = 0; u < 4; ++u)
        acc[t][u] = __builtin_amdgcn_mfma_f32_16x16x32_bf16(af[t], bfr[u], acc[t][u], 0, 0, 0);
  };

  stage(As0, Bs0, 0);
  asm volatile("s_waitcnt vmcnt(0)" ::: "memory");
  BAR;

  const int NT = K >> 5;
  for (int t = 0; t < NT; t += 2) {
    stage(As1, Bs1, (t + 1) << 5);
    asm volatile("s_waitcnt vmcnt(4)" ::: "memory");
    BAR;
    compute(As0, Bs0);
    BAR;
    if (t + 2 < NT) {
      stage(As0, Bs0, (t + 2) << 5);
      asm volatile("s_waitcnt vmcnt(4)" ::: "memory");
    } else {
      asm volatile("s_waitcnt vmcnt(0)" ::: "memory");
    }
    BAR;
    compute(As1, Bs1);
    BAR;
  }

#pragma unroll
  for (int t = 0; t < 4; ++t) {
#pragma unroll
    for (int u = 0; u < 4; ++u) {
      const long long col = n0 + wn * 64 + u * 16 + l15;
#pragma unroll
      for (int r = 0; r < 4; ++r) {
        const long long row = m0 + wm * 64 + t * 16 + (lane >> 4) * 4 + r;
        float v = acc[t][u][r];
        if constexpr (MODE == MODE_ATT) {
          // split-K partial buffers: [ks][h][i][j], plain coalesced stores
          ((float*)Cv)[((long long)(ks * 12 + batch) << 18) + (row << 9) + col] = v;
        } else if constexpr (MODE == MODE_OUTWS) {
          const long long n = col >> 6, kk = col & 63;
          ((unsigned short*)Cv)[(n * 512 + row) * 768 + (long long)batch * 64 + kk] = f2bf(v);
        } else {
          ((float*)Cv)[row * 768 + col] = v + alpha;  // unused modes
        }
      }
    }
  }
}

// softmax over last dim with 4-way split-K partial sum:
// att fp32 partials [4][12][512][512] -> bf16 [12][512][512]
__global__ __launch_bounds__(256) void softmax_rows(const float* __restrict__ att,
                                                    unsigned short* __restrict__ outb) {
  const long long rowbase = (long long)blockIdx.x << 9;
  const int tid = threadIdx.x;
  float a = 0.0f, b = 0.0f;
#pragma unroll
  for (int s = 0; s < 4; ++s) {
    a += att[(long long)s * 3145728 + rowbase + tid];
    b += att[(long long)s * 3145728 + rowbase + tid + 256];
  }

  float m = fmaxf(a, b);
#pragma unroll
  for (int off = 32; off; off >>= 1) m = fmaxf(m, __shfl_down(m, off));
  __shared__ float redm[4];
  if ((tid & 63) == 0) redm[tid >> 6] = m;
  __syncthreads();
  m = fmaxf(fmaxf(redm[0], redm[1]), fmaxf(redm[2], redm[3]));

  const float e0 = __expf(a - m), e1 = __expf(b - m);
  float s = e0 + e1;
#pragma unroll
  for (int off = 32; off; off >>= 1) s += __shfl_down(s, off);
  __shared__ float reds[4];
  if ((tid & 63) == 0) reds[tid >> 6] = s;
  __syncthreads();
  s = reds[0] + reds[1] + reds[2] + reds[3];

  const float inv = 1.0f / s;
  outb[rowbase + tid] = f2bf(e0 * inv);
  outb[rowbase + tid + 256] = f2bf(e1 * inv);
}

// Fused fp32 -> bf16 for ALL seven tensors, MLP-optimized: 64 elems/thread,
// 16 independent lane-contiguous nontemporal float4 loads, 16 uint2 stores.
// Grid 4752: Q/K/V = 1536 blocks each; 4 weights = 36 blocks each.
__global__ __launch_bounds__(256) void cvt_all(
    const float* __restrict__ q, const float* __restrict__ k,
    const float* __restrict__ v, const float* __restrict__ wq,
    const float* __restrict__ wk, const float* __restrict__ wv,
    const float* __restrict__ wo, unsigned short* __restrict__ dq,
    unsigned short* __restrict__ dk, unsigned short* __restrict__ dv,
    unsigned short* __restrict__ dwq, unsigned short* __restrict__ dwk,
    unsigned short* __restrict__ dwv, unsigned short* __restrict__ dwo) {
  const int b = blockIdx.x;
  const float* s;
  unsigned short* d;
  long long blk;
  if (b < 1536) { s = q; d = dq; blk = b; }
  else if (b < 3072) { s = k; d = dk; blk = b - 1536; }
  else if (b < 4608) { s = v; d = dv; blk = b - 3072; }
  else {
    const int w = b - 4608;
    const int t = w / 36;
    blk = w % 36;
    s = t == 0 ? wq : (t == 1 ? wk : (t == 2 ? wv : wo));
    d = t == 0 ? dwq : (t == 1 ? dwk : (t == 2 ? dwv : dwo));
  }
  const long long base = blk * 16384;
  const int tid = threadIdx.x;

  f32x4 r[16];
#pragma unroll
  for (int c = 0; c < 16; ++c)
    r[c] = __builtin_nontemporal_load(
        (const f32x4*)(s + base + (long long)(c * 256 + tid) * 4));
#pragma unroll
  for (int c = 0; c < 16; ++c) {
    uint2 p;
    p.x = (unsigned)f2bf(r[c][0]) | ((unsigned)f2bf(r[c][1]) << 16);
    p.y = (unsigned)f2bf(r[c][2]) | ((unsigned)f2bf(r[c][3]) << 16);
    *(uint2*)(d + base + (long long)(c * 256 + tid) * 4) = p;
  }
}

extern "C" void kernel_launch(void* const* d_in, const int* in_sizes, int n_in,
                              void* d_out, int out_size, void* d_ws, size_t ws_size,
                              hipStream_t stream) {
  const float* query = (const float*)d_in[0];
  const float* key   = (const float*)d_in[1];
  const float* value = (const float*)d_in[2];
  const float* Wq = (const float*)d_in[3];
  const float* bq = (const float*)d_in[4];
  const float* Wk = (const float*)d_in[5];
  const float* bk = (const float*)d_in[6];
  const float* Wv = (const float*)d_in[7];
  const float* bv = (const float*)d_in[8];
  const float* Wo = (const float*)d_in[9];
  const float* bo = (const float*)d_in[10];
  float* out = (float*)d_out;

  char* ws = (char*)d_ws;
  unsigned short* q_ws  = (unsigned short*)(ws);               // 50,331,648 B
  unsigned short* k_ws  = (unsigned short*)(ws + 50331648);    // 50,331,648 B
  unsigned short* vt_ws = (unsigned short*)(ws + 100663296);   // 50,331,648 B
  // bf16 weights, contiguous (b_bs = 589824 shorts strides wq->wk->wv)
  unsigned short* wq_b  = (unsigned short*)(ws + 150994944);
  unsigned short* wk_b  = (unsigned short*)(ws + 150994944 + 1179648);
  unsigned short* wv_b  = (unsigned short*)(ws + 150994944 + 2359296);
  unsigned short* wo_b  = (unsigned short*)(ws + 150994944 + 3538944);
  unsigned short* att_b = k_ws;   // k_ws dead after s2
  unsigned short* out_ws = q_ws;  // q_ws dead after s2
  // d_out scratch: xb0/xb1 bf16 Q/K inputs (dead after s1b);
  // att partials overlay xb1's region (xb1 dead after s1b).
  unsigned short* xb0 = (unsigned short*)d_out;                 // 50,331,648 B
  unsigned short* xb1 = (unsigned short*)d_out + 25165824;      // 50,331,648 B
  // V-bf16 input parks in k_ws: consumed by s1c (V-proj) BEFORE s1b
  // overwrites k_ws with the K projection (stream-serialized).
  unsigned short* xbv = k_ws;
  float* att_part = (float*)((char*)d_out + 50331648);          // 4 x 12,582,912 B

  const dim3 blk(256);
  const dim3 blk5(512);

  // s0: ALL fp32 -> bf16 conversions in one MLP-deep launch.
  cvt_all<<<4752, blk, 0, stream>>>(query, key, value, Wq, Wk, Wv, Wo,
                                    xb0, xb1, xbv, wq_b, wk_b, wv_b, wo_b);

  // s1c: V projection FIRST (reads xbv=k_ws, writes vt_ws)
  gemm256<MODE_VT><<<dim3(384, 1, 1), blk5, 0, stream>>>(
      xbv, wv_b, bv, nullptr, vt_ws, 768, 768, 768, 0, 0, 1.0f, 1.0f, 0, 3);

  // s1b: Q and K projections batched (z=2); batch1 output overwrites k_ws
  gemm256<MODE_QCAT><<<dim3(384, 1, 2), blk5, 0, stream>>>(
      xb0, wq_b, bq, bk, q_ws, 768, 768, 768, 25165824LL, 589824LL,
      0.015625f, 1.0f, 25165824LL, 3);

  // s2: tied scores on gemm256, per-head [512 x 4096] @ [512 x 4096]^T,
  //     split-K x4 (K-slice 1024, NT=16) -> 4 plain partial buffers
  //     in d_out's second half.
  gemm256<MODE_ATT><<<dim3(4, 1, 48), blk5, 0, stream>>>(
      q_ws, k_ws, nullptr, nullptr, att_part, 1024, 4096, 4096,
      2097152LL, 2097152LL, 1.0f, 1.0f, 0, 0);

  // s3: softmax (sums the 4 partials)
  softmax_rows<<<6144, blk, 0, stream>>>(att_part, att_b);

  // s4: per-head att @ Vt^T -> out_ws [(n*512+i)][h*64+k] (gemm_bt, locality map)
  gemm_bt<MODE_OUTWS, true, 1><<<dim3(1536, 1, 1), blk, 0, stream>>>(
      att_b, vt_ws, nullptr, out_ws, 512, 512, 512, 262144LL, 2097152LL,
      1.0f, 0, 0);

  // s5: output projection -> fp32 d_out on gemm256
  gemm256<MODE_OUT_BIAS><<<dim3(384, 1, 1), blk5, 0, stream>>>(
      out_ws, wo_b, bo, nullptr, out, 768, 768, 768, 0, 0, 1.0f, 1.0f, 0, 3);
}

// Round 17
// 551.018 us; speedup vs baseline: 1.0513x; 1.0399x over previous
//
#include <hip/hip_runtime.h>

// ---------------------------------------------------------------------------
// TiedMultiheadAttention  (B=1, N=64, L=512, D=768, H=12, DK=64)
//
// R19: R14/R18 locked config + ONE zero-risk tweak: XCD-locality remap in
//      gemm256's ATT block map. The 4 tiles of one z=(head,ks) share a 4MB
//      Q+K panel pair (= one XCD L2); remap puts them at dispatch indices
//      congruent mod 8 -> same XCD (bijective: lin = z*4+x;
//      zz=(lin>>5)*8+(lin&7); tile=(lin>>3)&3). Everything else identical.
// ---------------------------------------------------------------------------

typedef __bf16 bf16x8 __attribute__((ext_vector_type(8)));
typedef float f32x4 __attribute__((ext_vector_type(4)));

__device__ __forceinline__ unsigned short f2bf(float f) {
  unsigned u = __float_as_uint(f);
  u += 0x7fffu + ((u >> 16) & 1u);  // RNE
  return (unsigned short)(u >> 16);
}

__device__ __forceinline__ void gll16(const void* g, void* l) {
  __builtin_amdgcn_global_load_lds(
      (const __attribute__((address_space(1))) unsigned int*)g,
      (__attribute__((address_space(3))) unsigned int*)l, 16, 0, 0);
}

#define BAR __builtin_amdgcn_s_barrier()

enum { MODE_QCAT = 0, MODE_VT = 1, MODE_ATT = 2, MODE_OUTWS = 3, MODE_OUT_BIAS = 4 };

// ========================= gemm256: 256x256x64, 8 waves =====================
// C = A @ B^T, A:[M,K] bf16, B:[N,K] bf16. Per-wave 128x64 output, acc[8][4].
// LDS: 2 buf x (A,B) x 32KB = 128 KiB. Stage unit = 8KB quarter (64 rows x 64
// cols) = 1 gll/wave. Slot-XOR involution on A/B reads (source pre-swizzled).
// Per tile T (4 phases, kc=p>>1, mhalf=p&1):
//   p0: stage B0,B1(T+1)   p1: stage B2,B3(T+1)
//   p2: stage A1,A3(T+1)   p3: stage A0,A2(T+2)
// Boundary: vmcnt(2) (the two T+2 quarters stay in flight), barrier.
// Block maps:
//   QCAT/VT/OUT_BIAS: generic XCD swizzle (ntn), batch = blockIdx.z.
//   ATT: grid (4,1,48), XCD-locality remap: lin = z*4+x (dispatch order);
//        zz = (lin>>5)*8 + (lin&7)  [the 4 tiles of one zz are congruent
//        mod 8 -> same XCD L2]; tile = (lin>>3)&3; head = zz%12, ks = zz/12.
//        K = 1024 slice, A/B advanced by ks*K; C = fp32 partial [ks*12+h].
template <int MODE>
__global__ __launch_bounds__(512, 2) void gemm256(
    const void* __restrict__ Av, const void* __restrict__ Bv,
    const float* __restrict__ b0, const float* __restrict__ b1,
    void* __restrict__ Cv, int K, int lda, int ldb,
    long long a_bs, long long b_bs, float alpha0, float alpha1,
    long long c_bs, int ntn) {
  __shared__ unsigned short L[2][2][16384];

  const int tid = threadIdx.x;
  const int wave = tid >> 6;
  const int lane = tid & 63;
  const int wm = wave >> 2;   // 0..1
  const int wn = wave & 3;    // 0..3
  const int l15 = lane & 15;
  const int kq8 = lane >> 4;  // 0..3
  const int sw = l15 & 7;

  int tm, tn, batch, ks = 0;
  if constexpr (MODE == MODE_ATT) {
    const int lin = blockIdx.z * 4 + blockIdx.x;      // dispatch-linear 0..191
    const int zz = ((lin >> 5) << 3) + (lin & 7);     // 0..47; tiles of zz share XCD
    const int tile = (lin >> 3) & 3;
    tm = tile >> 1;
    tn = tile & 1;
    batch = zz % 12;   // head
    ks = zz / 12;      // 0..3 split-K slice
  } else {
    const int bid = blockIdx.x;
    const int xcd = bid & 7;
    const int kk_ = bid >> 3;
    tn = kk_ % ntn;
    tm = (kk_ / ntn) * 8 + xcd;
    batch = blockIdx.z;
  }

  const long long m0 = (long long)tm * 256;
  const long long n0 = (long long)tn * 256;

  const unsigned short* Ab = (const unsigned short*)Av + (long long)batch * a_bs +
                             (long long)ks * K;
  const unsigned short* Bb = (const unsigned short*)Bv + (long long)batch * b_bs +
                             (long long)ks * K;

  const long long rowAw = m0 + wave * 8 + (lane >> 3);
  const long long rowBw = n0 + wave * 8 + (lane >> 3);
  const int csw = ((lane & 7) ^ (lane >> 3)) << 3;  // pre-swizzled col (elems)

  f32x4 acc[8][4] = {};

  auto stA = [&](int buf, int q, int k0) {
    gll16(Ab + (rowAw + (q << 6)) * (long long)lda + k0 + csw,
          &L[buf][0][(q << 12) + (wave << 9)]);
  };
  auto stB = [&](int buf, int q, int k0) {
    gll16(Bb + (rowBw + (q << 6)) * (long long)ldb + k0 + csw,
          &L[buf][1][(q << 12) + (wave << 9)]);
  };

  // bias preload (no VMEM inside the K-loop except staging glls)
  float bpre[4] = {};
  float aa = 1.0f;
  if constexpr (MODE == MODE_QCAT || MODE == MODE_VT || MODE == MODE_OUT_BIAS) {
    const float* bb = batch ? b1 : b0;
    aa = batch ? alpha1 : alpha0;
#pragma unroll
    for (int u = 0; u < 4; ++u) bpre[u] = bb[n0 + wn * 64 + u * 16 + l15];
  }

  // Prologue: tile 0 fully, then A0,A2 of tile 1 (the 2 allowed in flight).
  const int NT = K >> 6;
#pragma unroll
  for (int q = 0; q < 4; ++q) stB(0, q, 0);
#pragma unroll
  for (int q = 0; q < 4; ++q) stA(0, q, 0);
  if (NT > 1) {
    stA(1, 0, 64);
    stA(1, 2, 64);
    asm volatile("s_waitcnt vmcnt(2)" ::: "memory");
  } else {
    asm volatile("s_waitcnt vmcnt(0)" ::: "memory");
  }
  BAR;

  for (int T = 0; T < NT; ++T) {
    const int cur = T & 1, nxt = cur ^ 1;
    const int k1 = (T + 1) << 6, k2 = (T + 2) << 6;
#pragma unroll
    for (int p = 0; p < 4; ++p) {
      const int kc = p >> 1, mh = p & 1;
      bf16x8 af[4], bfr[4];
#pragma unroll
      for (int mf = 0; mf < 4; ++mf) {
        const int row = wm * 128 + mh * 64 + mf * 16 + l15;
        af[mf] = *(const bf16x8*)&L[cur][0][row * 64 + (((kc << 2) + kq8) ^ sw) * 8];
      }
#pragma unroll
      for (int u = 0; u < 4; ++u) {
        const int row = wn * 64 + u * 16 + l15;
        bfr[u] = *(const bf16x8*)&L[cur][1][row * 64 + (((kc << 2) + kq8) ^ sw) * 8];
      }
      if (p == 0 && T + 1 < NT) { stB(nxt, 0, k1); stB(nxt, 1, k1); }
      if (p == 1 && T + 1 < NT) { stB(nxt, 2, k1); stB(nxt, 3, k1); }
      if (p == 2 && T + 1 < NT) { stA(nxt, 1, k1); stA(nxt, 3, k1); }
      if (p == 3 && T + 2 < NT) { stA(cur, 0, k2); stA(cur, 2, k2); }
      __builtin_amdgcn_s_setprio(1);
#pragma unroll
      for (int mf = 0; mf < 4; ++mf)
#pragma unroll
        for (int u = 0; u < 4; ++u)
          acc[mh * 4 + mf][u] = __builtin_amdgcn_mfma_f32_16x16x32_bf16(
              af[mf], bfr[u], acc[mh * 4 + mf][u], 0, 0, 0);
      __builtin_amdgcn_s_setprio(0);
      if (p == 3) {
        if (T + 1 < NT) {
          if (T + 2 < NT) asm volatile("s_waitcnt vmcnt(2)" ::: "memory");
          else            asm volatile("s_waitcnt vmcnt(0)" ::: "memory");
          BAR;
        }
      } else {
        BAR;
      }
    }
  }

  // Epilogue
#pragma unroll
  for (int mf = 0; mf < 8; ++mf) {
#pragma unroll
    for (int u = 0; u < 4; ++u) {
      const long long col = n0 + wn * 64 + u * 16 + l15;
#pragma unroll
      for (int r = 0; r < 4; ++r) {
        const long long row = m0 + wm * 128 + mf * 16 + (lane >> 4) * 4 + r;
        float v = acc[mf][u][r];
        if constexpr (MODE == MODE_QCAT) {
          const float vv = (v + bpre[u]) * aa;
          const long long h = col >> 6, kq = col & 63, n = row >> 9, i = row & 511;
          ((unsigned short*)Cv + batch * c_bs)[((h * 512 + i) << 12) + (n << 6) + kq] =
              f2bf(vv);
        } else if constexpr (MODE == MODE_VT) {
          const float vv = v + bpre[u];
          const long long h = col >> 6, kq = col & 63, n = row >> 9, j = row & 511;
          ((unsigned short*)Cv)[(((h << 12) + (n << 6) + kq) << 9) + j] = f2bf(vv);
        } else if constexpr (MODE == MODE_ATT) {
          // fp32 partial [ks*12+head][i][j], plain coalesced stores
          ((float*)Cv)[((long long)(ks * 12 + batch) << 18) + (row << 9) + col] = v;
        } else {  // MODE_OUT_BIAS
          ((float*)Cv)[row * 768 + col] = v + bpre[u];
        }
      }
    }
  }
}

// ================== R5/R10 128x128 kernel (s4) ==============================
constexpr int BM = 128, BN = 128, BK = 32;

template <int MODE, bool SWZ, int KS>
__global__ __launch_bounds__(256, 2) void gemm_bt(
    const void* __restrict__ Av, const void* __restrict__ Bv,
    const float* __restrict__ bias, void* __restrict__ Cv,
    int K, int lda, int ldb, long long a_bs, long long b_bs,
    float alpha, int ntn, long long c_bs) {
  constexpr int LP = 32;

  __shared__ unsigned short As0[BM * LP];
  __shared__ unsigned short Bs0[BN * LP];
  __shared__ unsigned short As1[BM * LP];
  __shared__ unsigned short Bs1[BN * LP];

  const int tid = threadIdx.x;
  const int wave = tid >> 6;
  const int lane = tid & 63;
  const int wm = wave >> 1, wn = wave & 1;

  int tm, tn, batch = 0, ks = 0;
  if constexpr (SWZ && MODE == MODE_ATT) {
    const int bid = blockIdx.x;
    const int xcd = bid & 7, j = bid >> 3;
    const int z = (j >> 4) * 8 + xcd;   // 0..47, z%8 == xcd
    const int tile = j & 15;
    tn = tile & 3;
    tm = tile >> 2;
    ks = z % KS;
    batch = z / KS;
  } else if constexpr (SWZ && MODE == MODE_OUTWS) {
    const int bid = blockIdx.x;
    const int xcd = bid & 7, j = bid >> 3;
    const int g = (j >> 6) * 8 + xcd;   // 0..23, g%8 == xcd
    const int idx = j & 63;
    batch = g >> 1;                     // head
    tm = idx >> 4;
    tn = (g & 1) * 16 + (idx & 15);
  } else {
    tn = blockIdx.x;
    tm = blockIdx.y;
    batch = blockIdx.z;
    if constexpr (KS > 1) { ks = batch % KS; batch /= KS; }
  }

  const long long m0 = (long long)tm * BM;
  const long long n0 = (long long)tn * BN;

  const unsigned short* Ab = (const unsigned short*)Av + (long long)batch * a_bs + (long long)ks * K;
  const unsigned short* Bb = (const unsigned short*)Bv + (long long)batch * b_bs + (long long)ks * K;

  f32x4 acc[4][4] = {};

  const int l15 = lane & 15;
  const int kq = (lane >> 4) * 8;
  const int r_in = lane >> 2;
  const int c8 = (lane & 3) * 8;

  auto stage = [&](unsigned short* Asb, unsigned short* Bsb, int k0) {
#pragma unroll
    for (int t = 0; t < 2; ++t) {
      const int rb = t * 64 + wave * 16;
      gll16(Ab + (m0 + rb + r_in) * (long long)lda + k0 + c8, &Asb[rb * LP]);
      gll16(Bb + (n0 + rb + r_in) * (long long)ldb + k0 + c8, &Bsb[rb * LP]);
    }
  };
  auto compute = [&](const unsigned short* Asb, const unsigned short* Bsb) {
    bf16x8 af[4], bfr[4];
#pragma unroll
    for (int t = 0; t < 4; ++t)
      af[t] = *(const bf16x8*)&Asb[(wm * 64 + t * 16 + l15) * LP + kq];
#pragma unroll
    for (int u = 0; u < 4; ++u)
      bfr[u] = *(const bf16x8*)&Bsb[(wn * 64 + u * 16 + l15) * LP + kq];
#pragma unroll
    for (int t = 0; t < 4; ++t)
#pragma unroll
      for (int u = 0; u < 4; ++u)
        acc[t][u] = __builtin_amdgcn_mfma_f32_16x16x32_bf16(af[t], bfr[u], acc[t][u], 0, 0, 0);
  };

  stage(As0, Bs0, 0);
  asm volatile("s_waitcnt vmcnt(0)" ::: "memory");
  BAR;

  const int NT = K >> 5;
  for (int t = 0; t < NT; t += 2) {
    stage(As1, Bs1, (t + 1) << 5);
    asm volatile("s_waitcnt vmcnt(4)" ::: "memory");
    BAR;
    compute(As0, Bs0);
    BAR;
    if (t + 2 < NT) {
      stage(As0, Bs0, (t + 2) << 5);
      asm volatile("s_waitcnt vmcnt(4)" ::: "memory");
    } else {
      asm volatile("s_waitcnt vmcnt(0)" ::: "memory");
    }
    BAR;
    compute(As1, Bs1);
    BAR;
  }

#pragma unroll
  for (int t = 0; t < 4; ++t) {
#pragma unroll
    for (int u = 0; u < 4; ++u) {
      const long long col = n0 + wn * 64 + u * 16 + l15;
#pragma unroll
      for (int r = 0; r < 4; ++r) {
        const long long row = m0 + wm * 64 + t * 16 + (lane >> 4) * 4 + r;
        float v = acc[t][u][r];
        if constexpr (MODE == MODE_ATT) {
          // split-K partial buffers: [ks][h][i][j], plain coalesced stores
          ((float*)Cv)[((long long)(ks * 12 + batch) << 18) + (row << 9) + col] = v;
        } else if constexpr (MODE == MODE_OUTWS) {
          const long long n = col >> 6, kk = col & 63;
          ((unsigned short*)Cv)[(n * 512 + row) * 768 + (long long)batch * 64 + kk] = f2bf(v);
        } else {
          ((float*)Cv)[row * 768 + col] = v + alpha;  // unused modes
        }
      }
    }
  }
}

// softmax over last dim with 4-way split-K partial sum:
// att fp32 partials [4][12][512][512] -> bf16 [12][512][512]
__global__ __launch_bounds__(256) void softmax_rows(const float* __restrict__ att,
                                                    unsigned short* __restrict__ outb) {
  const long long rowbase = (long long)blockIdx.x << 9;
  const int tid = threadIdx.x;
  float a = 0.0f, b = 0.0f;
#pragma unroll
  for (int s = 0; s < 4; ++s) {
    a += att[(long long)s * 3145728 + rowbase + tid];
    b += att[(long long)s * 3145728 + rowbase + tid + 256];
  }

  float m = fmaxf(a, b);
#pragma unroll
  for (int off = 32; off; off >>= 1) m = fmaxf(m, __shfl_down(m, off));
  __shared__ float redm[4];
  if ((tid & 63) == 0) redm[tid >> 6] = m;
  __syncthreads();
  m = fmaxf(fmaxf(redm[0], redm[1]), fmaxf(redm[2], redm[3]));

  const float e0 = __expf(a - m), e1 = __expf(b - m);
  float s = e0 + e1;
#pragma unroll
  for (int off = 32; off; off >>= 1) s += __shfl_down(s, off);
  __shared__ float reds[4];
  if ((tid & 63) == 0) reds[tid >> 6] = s;
  __syncthreads();
  s = reds[0] + reds[1] + reds[2] + reds[3];

  const float inv = 1.0f / s;
  outb[rowbase + tid] = f2bf(e0 * inv);
  outb[rowbase + tid + 256] = f2bf(e1 * inv);
}

// Fused fp32 -> bf16 for ALL seven tensors, MLP-optimized: 64 elems/thread,
// 16 independent lane-contiguous nontemporal float4 loads, 16 uint2 stores.
// Grid 4752: Q/K/V = 1536 blocks each; 4 weights = 36 blocks each.
__global__ __launch_bounds__(256) void cvt_all(
    const float* __restrict__ q, const float* __restrict__ k,
    const float* __restrict__ v, const float* __restrict__ wq,
    const float* __restrict__ wk, const float* __restrict__ wv,
    const float* __restrict__ wo, unsigned short* __restrict__ dq,
    unsigned short* __restrict__ dk, unsigned short* __restrict__ dv,
    unsigned short* __restrict__ dwq, unsigned short* __restrict__ dwk,
    unsigned short* __restrict__ dwv, unsigned short* __restrict__ dwo) {
  const int b = blockIdx.x;
  const float* s;
  unsigned short* d;
  long long blk;
  if (b < 1536) { s = q; d = dq; blk = b; }
  else if (b < 3072) { s = k; d = dk; blk = b - 1536; }
  else if (b < 4608) { s = v; d = dv; blk = b - 3072; }
  else {
    const int w = b - 4608;
    const int t = w / 36;
    blk = w % 36;
    s = t == 0 ? wq : (t == 1 ? wk : (t == 2 ? wv : wo));
    d = t == 0 ? dwq : (t == 1 ? dwk : (t == 2 ? dwv : dwo));
  }
  const long long base = blk * 16384;
  const int tid = threadIdx.x;

  f32x4 r[16];
#pragma unroll
  for (int c = 0; c < 16; ++c)
    r[c] = __builtin_nontemporal_load(
        (const f32x4*)(s + base + (long long)(c * 256 + tid) * 4));
#pragma unroll
  for (int c = 0; c < 16; ++c) {
    uint2 p;
    p.x = (unsigned)f2bf(r[c][0]) | ((unsigned)f2bf(r[c][1]) << 16);
    p.y = (unsigned)f2bf(r[c][2]) | ((unsigned)f2bf(r[c][3]) << 16);
    *(uint2*)(d + base + (long long)(c * 256 + tid) * 4) = p;
  }
}

extern "C" void kernel_launch(void* const* d_in, const int* in_sizes, int n_in,
                              void* d_out, int out_size, void* d_ws, size_t ws_size,
                              hipStream_t stream) {
  const float* query = (const float*)d_in[0];
  const float* key   = (const float*)d_in[1];
  const float* value = (const float*)d_in[2];
  const float* Wq = (const float*)d_in[3];
  const float* bq = (const float*)d_in[4];
  const float* Wk = (const float*)d_in[5];
  const float* bk = (const float*)d_in[6];
  const float* Wv = (const float*)d_in[7];
  const float* bv = (const float*)d_in[8];
  const float* Wo = (const float*)d_in[9];
  const float* bo = (const float*)d_in[10];
  float* out = (float*)d_out;

  char* ws = (char*)d_ws;
  unsigned short* q_ws  = (unsigned short*)(ws);               // 50,331,648 B
  unsigned short* k_ws  = (unsigned short*)(ws + 50331648);    // 50,331,648 B
  unsigned short* vt_ws = (unsigned short*)(ws + 100663296);   // 50,331,648 B
  // bf16 weights, contiguous (b_bs = 589824 shorts strides wq->wk->wv)
  unsigned short* wq_b  = (unsigned short*)(ws + 150994944);
  unsigned short* wk_b  = (unsigned short*)(ws + 150994944 + 1179648);
  unsigned short* wv_b  = (unsigned short*)(ws + 150994944 + 2359296);
  unsigned short* wo_b  = (unsigned short*)(ws + 150994944 + 3538944);
  unsigned short* att_b = k_ws;   // k_ws dead after s2
  unsigned short* out_ws = q_ws;  // q_ws dead after s2
  // d_out scratch: xb0/xb1 bf16 Q/K inputs (dead after s1b);
  // att partials overlay xb1's region (xb1 dead after s1b).
  unsigned short* xb0 = (unsigned short*)d_out;                 // 50,331,648 B
  unsigned short* xb1 = (unsigned short*)d_out + 25165824;      // 50,331,648 B
  // V-bf16 input parks in k_ws: consumed by s1c (V-proj) BEFORE s1b
  // overwrites k_ws with the K projection (stream-serialized).
  unsigned short* xbv = k_ws;
  float* att_part = (float*)((char*)d_out + 50331648);          // 4 x 12,582,912 B

  const dim3 blk(256);
  const dim3 blk5(512);

  // s0: ALL fp32 -> bf16 conversions in one MLP-deep launch.
  cvt_all<<<4752, blk, 0, stream>>>(query, key, value, Wq, Wk, Wv, Wo,
                                    xb0, xb1, xbv, wq_b, wk_b, wv_b, wo_b);

  // s1c: V projection FIRST (reads xbv=k_ws, writes vt_ws)
  gemm256<MODE_VT><<<dim3(384, 1, 1), blk5, 0, stream>>>(
      xbv, wv_b, bv, nullptr, vt_ws, 768, 768, 768, 0, 0, 1.0f, 1.0f, 0, 3);

  // s1b: Q and K projections batched (z=2); batch1 output overwrites k_ws
  gemm256<MODE_QCAT><<<dim3(384, 1, 2), blk5, 0, stream>>>(
      xb0, wq_b, bq, bk, q_ws, 768, 768, 768, 25165824LL, 589824LL,
      0.015625f, 1.0f, 25165824LL, 3);

  // s2: tied scores on gemm256, per-head [512 x 4096] @ [512 x 4096]^T,
  //     split-K x4 (K-slice 1024, NT=16), XCD-locality remap -> 4 plain
  //     partial buffers in d_out's second half.
  gemm256<MODE_ATT><<<dim3(4, 1, 48), blk5, 0, stream>>>(
      q_ws, k_ws, nullptr, nullptr, att_part, 1024, 4096, 4096,
      2097152LL, 2097152LL, 1.0f, 1.0f, 0, 0);

  // s3: softmax (sums the 4 partials)
  softmax_rows<<<6144, blk, 0, stream>>>(att_part, att_b);

  // s4: per-head att @ Vt^T -> out_ws [(n*512+i)][h*64+k] (gemm_bt, locality map)
  gemm_bt<MODE_OUTWS, true, 1><<<dim3(1536, 1, 1), blk, 0, stream>>>(
      att_b, vt_ws, nullptr, out_ws, 512, 512, 512, 262144LL, 2097152LL,
      1.0f, 0, 0);

  // s5: output projection -> fp32 d_out on gemm256
  gemm256<MODE_OUT_BIAS><<<dim3(384, 1, 1), blk5, 0, stream>>>(
      out_ws, wo_b, bo, nullptr, out, 768, 768, 768, 0, 0, 1.0f, 1.0f, 0, 3);
}